// Round 3
// baseline (9382.574 us; speedup 1.0000x reference)
//
#include <hip/hip_runtime.h>
#include <hip/hip_bf16.h>

typedef __attribute__((ext_vector_type(8))) short short8;
typedef __attribute__((ext_vector_type(4))) float floatx4;
typedef __attribute__((ext_vector_type(4))) int intx4;
typedef __attribute__((ext_vector_type(2))) unsigned int uint2v;

#define T_STEPS 512
#define BATCH   32
#define HDIM    1024
#define GATE4   4096
#define DA_DIM  64
#define PWG     128
#define RING    513
#define EPS_LN  1e-5f

// round-to-nearest-even fp32 -> bf16 bit pattern
__device__ __forceinline__ unsigned short f2bf(float f) {
    unsigned u = __float_as_uint(f);
    unsigned r = (u + 0x7FFFu + ((u >> 16) & 1u)) >> 16;
    return (unsigned short)r;
}

// device-coherent 16B write-through store: bypasses L1+L2 to coherence point
__device__ __forceinline__ void coh_store16(void* p, intx4 v) {
    asm volatile("global_store_dwordx4 %0, %1, off sc0 sc1" :: "v"(p), "v"(v) : "memory");
}
__device__ __forceinline__ void coh_store4(void* p, unsigned v) {
    asm volatile("global_store_dword %0, %1, off sc0 sc1" :: "v"(p), "v"(v) : "memory");
}
__device__ __forceinline__ void waitcnt_vm0() {
    asm volatile("s_waitcnt vmcnt(0)" ::: "memory");
}

// Poll all 128 WG flags (>= tgt) with one coherent dwordx2 load per lane.
__device__ __forceinline__ void poll_flags(const unsigned* flags, unsigned tgt, int lane) {
    const unsigned* p = flags + lane * 2;
    for (;;) {
        uint2v f;
        asm volatile("global_load_dwordx2 %0, %1, off sc0 sc1\n\t"
                     "s_waitcnt vmcnt(0)"
                     : "=v"(f) : "v"(p) : "memory");
        int ok = (f.x >= tgt) && (f.y >= tgt);
        if (__all(ok)) break;
        __builtin_amdgcn_s_sleep(1);
    }
}

// ---------------------------------------------------------------------------
// W fragment prep: wf[w][mt][kb][lane][j]  (A-operand layout, K=[x;h], 2048)
// ---------------------------------------------------------------------------
__global__ void __launch_bounds__(256) prep_wfrag(
    const float* __restrict__ Wih, const float* __restrict__ Whh,
    unsigned short* __restrict__ wf)
{
    int gid  = blockIdx.x * 256 + threadIdx.x;   // 4096*256 = 1,048,576
    int lane = gid & 63;
    int kb   = (gid >> 6) & 63;
    int mt   = (gid >> 12) & 1;
    int w    = gid >> 13;                        // 0..127
    int m    = lane & 15;
    int row  = (m >> 2) * HDIM + w * 8 + mt * 4 + (m & 3);
    int k0   = kb * 32 + (lane >> 4) * 8;
    const float* src = (k0 < HDIM) ? (Wih + (size_t)row * HDIM + k0)
                                   : (Whh + (size_t)row * HDIM + (k0 - HDIM));
    unsigned short* dst = wf + (size_t)gid * 8;
#pragma unroll
    for (int j = 0; j < 8; ++j) dst[j] = f2bf(src[j]);
}

// ---------------------------------------------------------------------------
// x fragment prep: per t, xf[t][kb][nb][lane][j]  (B-operand layout)
// ---------------------------------------------------------------------------
__global__ void __launch_bounds__(256) prep_xfrag(
    const float* __restrict__ x, unsigned short* __restrict__ xf)
{
    int gid  = blockIdx.x * 256 + threadIdx.x;   // 8192*256 = 2,097,152
    int lane = gid & 63;
    int nb   = (gid >> 6) & 1;
    int kb   = (gid >> 7) & 31;
    int t    = gid >> 12;
    int b    = nb * 16 + (lane & 15);
    int k0   = kb * 32 + (lane >> 4) * 8;
    const float* src = x + ((size_t)(t * BATCH + b)) * HDIM + k0;
    unsigned short* dst = xf + (size_t)t * 32768 + (((kb * 2 + nb) * 64 + lane) * 8);
#pragma unroll
    for (int j = 0; j < 8; ++j) dst[j] = f2bf(src[j]);
}

// ---------------------------------------------------------------------------
// Persistent LSTM layer: 128 WGs x 256 thr (1 WG/CU). WG w owns h-dims
// [w*8,w*8+8) = 32 gate rows. Weights live in VGPRs (32 short8/wave, loaded
// once). Sync: flat 128-flag vector, plain sc0sc1 stores + one dwordx2
// coherent poll per wave. h broadcast via 513-slot bf16 ring.
// ---------------------------------------------------------------------------
__global__ void __launch_bounds__(256, 1) lstm_persistent(
    const unsigned short* __restrict__ xf,
    const unsigned short* __restrict__ wf,
    unsigned short* __restrict__ ring,
    const float* __restrict__ bih, const float* __restrict__ bhh,
    float* __restrict__ cbuf,
    float* __restrict__ hs,
    unsigned* __restrict__ flags,
    int slot0)
{
    __shared__ float part[16 * 256];      // [v][mt*2+nb][m][n]
    __shared__ float gates[2 * 16 * 32];  // [mt][m][batch]
    __shared__ float bias_s[32];
    __shared__ intx4 hstage4[32];         // [batch] -> 8 bf16

    const int tid  = threadIdx.x;
    const int w    = blockIdx.x;
    const int lane = tid & 63;
    const int v    = tid >> 6;
    const unsigned short* wbase = wf + (size_t)w * 65536;

    // ---- weights -> registers (once per layer): 32 short8 = 128 VGPRs ----
    short8 wx[2][8], wh[2][8];
#pragma unroll
    for (int mt = 0; mt < 2; ++mt)
#pragma unroll
        for (int i = 0; i < 8; ++i) {
            wx[mt][i] = *(const short8*)(wbase + (size_t)((mt * 64 + v * 8 + i) * 64 + lane) * 8);
            wh[mt][i] = *(const short8*)(wbase + (size_t)((mt * 64 + 32 + v * 8 + i) * 64 + lane) * 8);
        }

    if (tid < 32) {
        int mt = tid >> 4, m = tid & 15;
        int row = (m >> 2) * HDIM + w * 8 + mt * 4 + (m & 3);
        bias_s[tid] = bih[row] + bhh[row];
    }
    const int hd = tid >> 5;          // 0..7 local h-dim
    const int bb = tid & 31;          // batch
    const int j  = w * 8 + hd;        // global h-dim
    float creg = cbuf[bb * HDIM + j];
    __syncthreads();

    int slot = slot0;                 // slot0 in [0,RING)
    for (int t = 0; t < T_STEPS; ++t) {
        const unsigned short* xb = xf + (size_t)t * 32768;

        // issue x loads (latency hidden under the flag poll)
        short8 xv[8][2];
#pragma unroll
        for (int i = 0; i < 8; ++i) {
            const unsigned short* xp = xb + (size_t)((v * 8 + i) * 128 + lane) * 8;
            xv[i][0] = *(const short8*)xp;
            xv[i][1] = *(const short8*)(xp + 512);
        }

        // wait for all WGs to have published h(t-1)
        poll_flags(flags, (unsigned)(slot0 + t), lane);

        // ring loads (flight overlapped with x-part MFMAs below)
        const unsigned short* rb = ring + (size_t)slot * 32768;
        short8 hv[8][2];
#pragma unroll
        for (int i = 0; i < 8; ++i) {
            const unsigned short* hp = rb + (size_t)((v * 8 + i) * 128 + lane) * 8;
            hv[i][0] = *(const short8*)hp;
            hv[i][1] = *(const short8*)(hp + 512);
        }

        floatx4 a00 = {0.f,0.f,0.f,0.f}, a01 = {0.f,0.f,0.f,0.f};
        floatx4 a10 = {0.f,0.f,0.f,0.f}, a11 = {0.f,0.f,0.f,0.f};
#pragma unroll
        for (int i = 0; i < 8; ++i) {
            a00 = __builtin_amdgcn_mfma_f32_16x16x32_bf16(wx[0][i], xv[i][0], a00, 0, 0, 0);
            a01 = __builtin_amdgcn_mfma_f32_16x16x32_bf16(wx[0][i], xv[i][1], a01, 0, 0, 0);
            a10 = __builtin_amdgcn_mfma_f32_16x16x32_bf16(wx[1][i], xv[i][0], a10, 0, 0, 0);
            a11 = __builtin_amdgcn_mfma_f32_16x16x32_bf16(wx[1][i], xv[i][1], a11, 0, 0, 0);
        }
#pragma unroll
        for (int i = 0; i < 8; ++i) {
            a00 = __builtin_amdgcn_mfma_f32_16x16x32_bf16(wh[0][i], hv[i][0], a00, 0, 0, 0);
            a01 = __builtin_amdgcn_mfma_f32_16x16x32_bf16(wh[0][i], hv[i][1], a01, 0, 0, 0);
            a10 = __builtin_amdgcn_mfma_f32_16x16x32_bf16(wh[1][i], hv[i][0], a10, 0, 0, 0);
            a11 = __builtin_amdgcn_mfma_f32_16x16x32_bf16(wh[1][i], hv[i][1], a11, 0, 0, 0);
        }

        // ---- cross-wave K reduction via LDS ----
        {
            int n = lane & 15, q = lane >> 4;
#pragma unroll
            for (int r = 0; r < 4; ++r) {
                int m16 = (q * 4 + r) * 16 + n;
                part[(v * 4 + 0) * 256 + m16] = a00[r];
                part[(v * 4 + 1) * 256 + m16] = a01[r];
                part[(v * 4 + 2) * 256 + m16] = a10[r];
                part[(v * 4 + 3) * 256 + m16] = a11[r];
            }
        }
        __syncthreads();
        {
            int m = tid >> 4, n = tid & 15;
            int m16 = m * 16 + n;
#pragma unroll
            for (int mt = 0; mt < 2; ++mt)
#pragma unroll
                for (int nb = 0; nb < 2; ++nb) {
                    int c = mt * 2 + nb;
                    float g = part[(0 * 4 + c) * 256 + m16]
                            + part[(1 * 4 + c) * 256 + m16]
                            + part[(2 * 4 + c) * 256 + m16]
                            + part[(3 * 4 + c) * 256 + m16];
                    gates[(mt * 16 + m) * 32 + nb * 16 + n] = g + bias_s[mt * 16 + m];
                }
        }
        __syncthreads();

        // ---- gate nonlinearities + c/h update (all 256 threads) ----
        {
            int r3 = hd & 3, mt = hd >> 2;
            float gi = gates[(mt * 16 +  0 + r3) * 32 + bb];
            float gf = gates[(mt * 16 +  4 + r3) * 32 + bb];
            float gg = gates[(mt * 16 +  8 + r3) * 32 + bb];
            float go = gates[(mt * 16 + 12 + r3) * 32 + bb];
            float i_ = 1.f / (1.f + __expf(-gi));
            float f_ = 1.f / (1.f + __expf(-gf));
            float g_ = tanhf(gg);
            float o_ = 1.f / (1.f + __expf(-go));
            creg = f_ * creg + i_ * g_;
            float h = o_ * tanhf(creg);
            hs[((size_t)t * BATCH + bb) * HDIM + j] = h;
            ((unsigned short*)&hstage4[bb])[hd] = f2bf(h);
        }
        __syncthreads();

        // ---- publish h(t) + flag (wave 0 only; others proceed) ----
        int slot_out = (slot + 1 == RING) ? 0 : slot + 1;
        if (v == 0) {
            if (tid < 32) {
                unsigned short* hn = ring + (size_t)slot_out * 32768;
                int kb2   = w >> 2;
                int lane2 = ((w & 3) << 4) | (tid & 15);
                coh_store16(hn + (size_t)((kb2 * 2 + (tid >> 4)) * 64 + lane2) * 8,
                            hstage4[tid]);
            }
            waitcnt_vm0();   // h stores at coherence point before flag
            if (tid == 0) coh_store4(flags + w, (unsigned)(slot0 + t + 1));
        }
        slot = slot_out;
    }
    cbuf[bb * HDIM + j] = creg;
}

// ---------------------------------------------------------------------------
// Adapter (x + up(relu(down(x)))) + LayerNorm, one WG per (t,b) row.
// ---------------------------------------------------------------------------
__global__ void __launch_bounds__(256) adapter_ln(
    const float* __restrict__ xin,
    const float* __restrict__ Adw, const float* __restrict__ Adb,
    const float* __restrict__ Auw, const float* __restrict__ Aub,
    const float* __restrict__ lng, const float* __restrict__ lnb,
    float* __restrict__ outf, unsigned short* __restrict__ xfout)
{
    __shared__ float xs[1024];
    __shared__ float dsv[DA_DIM];
    __shared__ float red[512];
    int tid = threadIdx.x;
    int row = blockIdx.x;               // t*32 + b
    const float* xr = xin + (size_t)row * HDIM;
    for (int k = tid; k < HDIM; k += 256) xs[k] = xr[k];
    __syncthreads();
    {   // down-proj: d[a] = relu(A_dw[a,:] @ x + A_db[a])
        int a = tid & 63, c4 = tid >> 6;
        const float4* wrow = (const float4*)(Adw + (size_t)a * HDIM + c4 * 256);
        const float*  xx = xs + c4 * 256;
        float p = 0.f;
#pragma unroll 8
        for (int k = 0; k < 64; ++k) {
            float4 wv = wrow[k];
            p += wv.x * xx[4*k] + wv.y * xx[4*k+1] + wv.z * xx[4*k+2] + wv.w * xx[4*k+3];
        }
        red[tid] = p;
    }
    __syncthreads();
    if (tid < DA_DIM) {
        float s = red[tid] + red[64 + tid] + red[128 + tid] + red[192 + tid] + Adb[tid];
        dsv[tid] = s > 0.f ? s : 0.f;
    }
    __syncthreads();
    float y[4]; float s1 = 0.f, s2 = 0.f;
#pragma unroll
    for (int r = 0; r < 4; ++r) {
        int jj = tid + 256 * r;
        float acc = xs[jj] + Aub[jj];
        const float4* urow = (const float4*)(Auw + (size_t)jj * DA_DIM);
#pragma unroll
        for (int a = 0; a < 16; ++a) {
            float4 uv = urow[a];
            acc += uv.x * dsv[4*a] + uv.y * dsv[4*a+1] + uv.z * dsv[4*a+2] + uv.w * dsv[4*a+3];
        }
        y[r] = acc; s1 += acc; s2 += acc * acc;
    }
    red[tid] = s1; red[256 + tid] = s2;
    __syncthreads();
    for (int off = 128; off > 0; off >>= 1) {
        if (tid < off) { red[tid] += red[tid + off]; red[256 + tid] += red[256 + tid + off]; }
        __syncthreads();
    }
    float mean = red[0] * (1.f / 1024.f);
    float var  = red[256] * (1.f / 1024.f) - mean * mean;
    float rstd = rsqrtf(var + EPS_LN);
#pragma unroll
    for (int r = 0; r < 4; ++r) {
        int jj = tid + 256 * r;
        float o = (y[r] - mean) * rstd * lng[jj] + lnb[jj];
        if (outf) outf[(size_t)row * HDIM + jj] = o;
        if (xfout) {
            int t = row >> 5, b = row & 31;
            int kb = jj >> 5;
            int lane2 = (((jj >> 3) & 3) << 4) | (b & 15);
            xfout[(size_t)t * 32768 + ((kb * 2 + (b >> 4)) * 64 + lane2) * 8 + (jj & 7)] = f2bf(o);
        }
    }
}

extern "C" void kernel_launch(void* const* d_in, const int* in_sizes, int n_in,
                              void* d_out, int out_size, void* d_ws, size_t ws_size,
                              hipStream_t stream)
{
    const float* x   = (const float*)d_in[0];
    const float* Wih = (const float*)d_in[1];
    const float* Whh = (const float*)d_in[2];
    const float* bih = (const float*)d_in[3];
    const float* bhh = (const float*)d_in[4];
    const float* Adw = (const float*)d_in[5];
    const float* Adb = (const float*)d_in[6];
    const float* Auw = (const float*)d_in[7];
    const float* Aub = (const float*)d_in[8];
    const float* lng = (const float*)d_in[9];
    const float* lnb = (const float*)d_in[10];
    float* out = (float*)d_out;

    // workspace carve (~84 MB)
    char* ws = (char*)d_ws;
    unsigned short* wfb  = (unsigned short*)ws; ws += (size_t)GATE4 * 2048 * 2;      // 16.78 MB
    unsigned short* xfb  = (unsigned short*)ws; ws += (size_t)T_STEPS * 32768 * 2;   // 33.55 MB
    unsigned short* ring = (unsigned short*)ws; ws += (size_t)RING * 32768 * 2;      // 33.62 MB
    float*    cbuf  = (float*)ws;    ws += (size_t)BATCH * HDIM * 4;                 // 128 KB
    unsigned* flags = (unsigned*)ws; ws += 2048;
    float* hs = out;   // alias hs onto d_out x-region (adapter is in-place safe)

    hipMemsetAsync(cbuf, 0, (size_t)BATCH * HDIM * 4, stream);
    hipMemsetAsync(ring, 0, 32768 * 2, stream);     // ring slot 0 = h0 = 0
    hipMemsetAsync(flags, 0, 2048, stream);         // flags monotonic across layers

    prep_xfrag<<<8192, 256, 0, stream>>>(x, xfb);

    for (int l = 0; l < 2; ++l) {
        prep_wfrag<<<4096, 256, 0, stream>>>(Wih + (size_t)l * GATE4 * HDIM,
                                             Whh + (size_t)l * GATE4 * HDIM, wfb);
        lstm_persistent<<<PWG, 256, 0, stream>>>(xfb, wfb, ring,
                                                 bih + (size_t)l * GATE4,
                                                 bhh + (size_t)l * GATE4,
                                                 cbuf, hs, flags,
                                                 (l * T_STEPS) % RING);

        const float* adw = Adw + (size_t)l * DA_DIM * HDIM;
        const float* adb = Adb + (size_t)l * DA_DIM;
        const float* auw = Auw + (size_t)l * HDIM * DA_DIM;
        const float* aub = Aub + (size_t)l * HDIM;
        const float* lg  = lng + (size_t)l * HDIM;
        const float* lb  = lnb + (size_t)l * HDIM;
        if (l == 0) {
            adapter_ln<<<T_STEPS * BATCH, 256, 0, stream>>>(hs, adw, adb, auw, aub, lg, lb,
                                                            nullptr, xfb);
        } else {
            hipMemcpyAsync(out + 16777216, hs + (size_t)511 * BATCH * HDIM,
                           (size_t)BATCH * HDIM * 4, hipMemcpyDeviceToDevice, stream);
            hipMemcpyAsync(out + 16777216 + 32768, cbuf,
                           (size_t)BATCH * HDIM * 4, hipMemcpyDeviceToDevice, stream);
            adapter_ln<<<T_STEPS * BATCH, 256, 0, stream>>>(hs, adw, adb, auw, aub, lg, lb,
                                                            out, nullptr);
        }
    }
}

// Round 4
// 7750.547 us; speedup vs baseline: 1.2106x; 1.2106x over previous
//
#include <hip/hip_runtime.h>
#include <hip/hip_bf16.h>

typedef __attribute__((ext_vector_type(8))) short short8;
typedef __attribute__((ext_vector_type(4))) float floatx4;
typedef __attribute__((ext_vector_type(4))) int intx4;
typedef __attribute__((ext_vector_type(2))) unsigned int uint2v;

#define T_STEPS 512
#define BATCH   32
#define HDIM    1024
#define GATE4   4096
#define DA_DIM  64
#define PWG     128
#define RING    513
#define AROWS   8
#define EPS_LN  1e-5f

// round-to-nearest-even fp32 -> bf16 bit pattern
__device__ __forceinline__ unsigned short f2bf(float f) {
    unsigned u = __float_as_uint(f);
    unsigned r = (u + 0x7FFFu + ((u >> 16) & 1u)) >> 16;
    return (unsigned short)r;
}

// device-coherent 16B write-through store (to coherence point / IF$)
__device__ __forceinline__ void coh_store16(void* p, intx4 v) {
    asm volatile("global_store_dwordx4 %0, %1, off sc0 sc1" :: "v"(p), "v"(v) : "memory");
}
__device__ __forceinline__ void coh_store4(void* p, unsigned v) {
    asm volatile("global_store_dword %0, %1, off sc0 sc1" :: "v"(p), "v"(v) : "memory");
}
__device__ __forceinline__ void waitcnt_vm0() {
    asm volatile("s_waitcnt vmcnt(0)" ::: "memory");
}

// Poll all 128 WG flags (>= tgt): one coherent dwordx2 per lane (wave 0 only).
__device__ __forceinline__ void poll_flags(const unsigned* flags, unsigned tgt, int lane) {
    const unsigned* p = flags + lane * 2;
    for (;;) {
        uint2v f;
        asm volatile("global_load_dwordx2 %0, %1, off sc0 sc1\n\t"
                     "s_waitcnt vmcnt(0)"
                     : "=v"(f) : "v"(p) : "memory");
        int ok = (f.x >= tgt) && (f.y >= tgt);
        if (__all(ok)) break;
        __builtin_amdgcn_s_sleep(1);
    }
}

// ---------------------------------------------------------------------------
// W fragment prep: wf[w][mt][kb][lane][j]  (A-operand layout, K=[x;h], 2048)
// ---------------------------------------------------------------------------
__global__ void __launch_bounds__(256) prep_wfrag(
    const float* __restrict__ Wih, const float* __restrict__ Whh,
    unsigned short* __restrict__ wf)
{
    int gid  = blockIdx.x * 256 + threadIdx.x;   // 1,048,576
    int lane = gid & 63;
    int kb   = (gid >> 6) & 63;
    int mt   = (gid >> 12) & 1;
    int w    = gid >> 13;                        // 0..127
    int m    = lane & 15;
    int row  = (m >> 2) * HDIM + w * 8 + mt * 4 + (m & 3);
    int k0   = kb * 32 + (lane >> 4) * 8;
    const float* src = (k0 < HDIM) ? (Wih + (size_t)row * HDIM + k0)
                                   : (Whh + (size_t)row * HDIM + (k0 - HDIM));
    unsigned short* dst = wf + (size_t)gid * 8;
#pragma unroll
    for (int j = 0; j < 8; ++j) dst[j] = f2bf(src[j]);
}

// ---------------------------------------------------------------------------
// x fragment prep: per t, xf[t][kb][nb][lane][j]  (B-operand layout)
// ---------------------------------------------------------------------------
__global__ void __launch_bounds__(256) prep_xfrag(
    const float* __restrict__ x, unsigned short* __restrict__ xf)
{
    int gid  = blockIdx.x * 256 + threadIdx.x;   // 2,097,152
    int lane = gid & 63;
    int nb   = (gid >> 6) & 1;
    int kb   = (gid >> 7) & 31;
    int t    = gid >> 12;
    int b    = nb * 16 + (lane & 15);
    int k0   = kb * 32 + (lane >> 4) * 8;
    const float* src = x + ((size_t)(t * BATCH + b)) * HDIM + k0;
    unsigned short* dst = xf + (size_t)t * 32768 + (((kb * 2 + nb) * 64 + lane) * 8);
#pragma unroll
    for (int j = 0; j < 8; ++j) dst[j] = f2bf(src[j]);
}

// ---------------------------------------------------------------------------
// Persistent LSTM layer: 128 WGs x 256 thr (1 WG/CU). WG w owns h-dims
// [w*8,w*8+8) = 32 gate rows. Weights LDS-resident (128 KB, staged once).
// Sync: flat 128-flag vector; wave 0 publishes (sc0sc1 + vmcnt drain) and
// polls; other waves park at __syncthreads. hs stores deferred past the flag.
// ---------------------------------------------------------------------------
__global__ void __launch_bounds__(256, 1) lstm_persistent(
    const unsigned short* __restrict__ xf,
    const unsigned short* __restrict__ wf,
    unsigned short* __restrict__ ring,
    const float* __restrict__ bih, const float* __restrict__ bhh,
    float* __restrict__ cbuf,
    float* __restrict__ hs,
    unsigned* __restrict__ flags,
    int slot0)
{
    __shared__ short8 wlds[8192];         // 128 KB: [mt*64 + (isH*32+kb)][lane]
    __shared__ float part[16 * 256];      // 16 KB
    __shared__ float gates[2 * 16 * 32];  // 4 KB
    __shared__ float bias_s[32];
    __shared__ intx4 hstage4[32];

    const int tid  = threadIdx.x;
    const int w    = blockIdx.x;
    const int lane = tid & 63;
    const int v    = tid >> 6;

    // ---- stage weights global -> LDS (once per layer) ----
    {
        const short8* wsrc = (const short8*)(wf + (size_t)w * 65536);
        for (int i = tid; i < 8192; i += 256) wlds[i] = wsrc[i];
    }
    if (tid < 32) {
        int mt = tid >> 4, m = tid & 15;
        int row = (m >> 2) * HDIM + w * 8 + mt * 4 + (m & 3);
        bias_s[tid] = bih[row] + bhh[row];
    }
    const int hd = tid >> 5;          // 0..7 local h-dim
    const int bb = tid & 31;          // batch
    const int j  = w * 8 + hd;        // global h-dim
    float creg = cbuf[bb * HDIM + j];
    __syncthreads();

    int slot = slot0;
    for (int t = 0; t < T_STEPS; ++t) {
        const unsigned short* xb = xf + (size_t)t * 32768;

        // x loads (global; L2-amortized per XCD)
        short8 xv[8][2];
#pragma unroll
        for (int i = 0; i < 8; ++i) {
            const unsigned short* xp = xb + (size_t)((v * 8 + i) * 128 + lane) * 8;
            xv[i][0] = *(const short8*)xp;
            xv[i][1] = *(const short8*)(xp + 512);
        }

        floatx4 a00 = {0.f,0.f,0.f,0.f}, a01 = {0.f,0.f,0.f,0.f};
        floatx4 a10 = {0.f,0.f,0.f,0.f}, a11 = {0.f,0.f,0.f,0.f};

        // ---- x-part MFMAs (A from LDS) — overlaps other WGs' publish ----
#pragma unroll
        for (int i = 0; i < 8; ++i) {
            int kb = v * 8 + i;
            short8 wa0 = wlds[(0 * 64 + kb) * 64 + lane];
            short8 wa1 = wlds[(1 * 64 + kb) * 64 + lane];
            a00 = __builtin_amdgcn_mfma_f32_16x16x32_bf16(wa0, xv[i][0], a00, 0, 0, 0);
            a01 = __builtin_amdgcn_mfma_f32_16x16x32_bf16(wa0, xv[i][1], a01, 0, 0, 0);
            a10 = __builtin_amdgcn_mfma_f32_16x16x32_bf16(wa1, xv[i][0], a10, 0, 0, 0);
            a11 = __builtin_amdgcn_mfma_f32_16x16x32_bf16(wa1, xv[i][1], a11, 0, 0, 0);
        }

        // ---- wait for h(t-1): wave 0 polls, others park at the barrier ----
        if (v == 0) poll_flags(flags, (unsigned)(slot0 + t), lane);
        __syncthreads();

        // ---- h-part: ring loads (plain; cold-line fresh, L2-amortized) ----
        const unsigned short* rb = ring + (size_t)slot * 32768;
        short8 hv[8][2];
#pragma unroll
        for (int i = 0; i < 8; ++i) {
            const unsigned short* hp = rb + (size_t)((v * 8 + i) * 128 + lane) * 8;
            hv[i][0] = *(const short8*)hp;
            hv[i][1] = *(const short8*)(hp + 512);
        }
#pragma unroll
        for (int i = 0; i < 8; ++i) {
            int kh = v * 8 + i;
            short8 wa0 = wlds[(0 * 64 + 32 + kh) * 64 + lane];
            short8 wa1 = wlds[(1 * 64 + 32 + kh) * 64 + lane];
            a00 = __builtin_amdgcn_mfma_f32_16x16x32_bf16(wa0, hv[i][0], a00, 0, 0, 0);
            a01 = __builtin_amdgcn_mfma_f32_16x16x32_bf16(wa0, hv[i][1], a01, 0, 0, 0);
            a10 = __builtin_amdgcn_mfma_f32_16x16x32_bf16(wa1, hv[i][0], a10, 0, 0, 0);
            a11 = __builtin_amdgcn_mfma_f32_16x16x32_bf16(wa1, hv[i][1], a11, 0, 0, 0);
        }

        // ---- cross-wave K reduction via LDS ----
        {
            int n = lane & 15, q = lane >> 4;
#pragma unroll
            for (int r = 0; r < 4; ++r) {
                int m16 = (q * 4 + r) * 16 + n;
                part[(v * 4 + 0) * 256 + m16] = a00[r];
                part[(v * 4 + 1) * 256 + m16] = a01[r];
                part[(v * 4 + 2) * 256 + m16] = a10[r];
                part[(v * 4 + 3) * 256 + m16] = a11[r];
            }
        }
        __syncthreads();
        {
            int m = tid >> 4, n = tid & 15;
            int m16 = m * 16 + n;
#pragma unroll
            for (int mt = 0; mt < 2; ++mt)
#pragma unroll
                for (int nb = 0; nb < 2; ++nb) {
                    int c = mt * 2 + nb;
                    float g = part[(0 * 4 + c) * 256 + m16]
                            + part[(1 * 4 + c) * 256 + m16]
                            + part[(2 * 4 + c) * 256 + m16]
                            + part[(3 * 4 + c) * 256 + m16];
                    gates[(mt * 16 + m) * 32 + nb * 16 + n] = g + bias_s[mt * 16 + m];
                }
        }
        __syncthreads();

        // ---- gate nonlinearities + c/h update (one (hd,bb) per thread) ----
        float hval;
        {
            int r3 = hd & 3, mt = hd >> 2;
            float gi = gates[(mt * 16 +  0 + r3) * 32 + bb];
            float gf = gates[(mt * 16 +  4 + r3) * 32 + bb];
            float gg = gates[(mt * 16 +  8 + r3) * 32 + bb];
            float go = gates[(mt * 16 + 12 + r3) * 32 + bb];
            float i_ = 1.f / (1.f + __expf(-gi));
            float f_ = 1.f / (1.f + __expf(-gf));
            float g_ = tanhf(gg);
            float o_ = 1.f / (1.f + __expf(-go));
            creg = f_ * creg + i_ * g_;
            hval = o_ * tanhf(creg);
            ((unsigned short*)&hstage4[bb])[hd] = f2bf(hval);
        }
        __syncthreads();

        // ---- publish h(t): wave 0 — 32x16B sc0sc1 + drain + flag ----
        int slot_out = (slot + 1 == RING) ? 0 : slot + 1;
        if (v == 0) {
            if (tid < 32) {
                unsigned short* hn = ring + (size_t)slot_out * 32768;
                int kb2   = w >> 2;
                int lane2 = ((w & 3) << 4) | (tid & 15);
                coh_store16(hn + (size_t)((kb2 * 2 + (tid >> 4)) * 64 + lane2) * 8,
                            hstage4[tid]);
            }
            waitcnt_vm0();
            if (tid == 0) coh_store4(flags + w, (unsigned)(slot0 + t + 1));
        }
        // hs history store AFTER the flag (not on the critical path)
        hs[((size_t)t * BATCH + bb) * HDIM + j] = hval;
        slot = slot_out;
    }
    cbuf[bb * HDIM + j] = creg;
}

// ---------------------------------------------------------------------------
// Adapter (x + up(relu(down(x)))) + LayerNorm. 8 rows per WG (2048 WGs):
// Adw/Auw streamed once per WG (L2 traffic /8), full-K per-thread dots.
// ---------------------------------------------------------------------------
__global__ void __launch_bounds__(256) adapter_ln(
    const float* __restrict__ xin,
    const float* __restrict__ Adw, const float* __restrict__ Adb,
    const float* __restrict__ Auw, const float* __restrict__ Aub,
    const float* __restrict__ lng, const float* __restrict__ lnb,
    float* __restrict__ outf, unsigned short* __restrict__ xfout)
{
    __shared__ float xs[AROWS * 1024];     // 32 KB
    __shared__ float dbuf[AROWS * 64];     // 2 KB
    __shared__ float red2[AROWS * 32 * 2]; // 2 KB
    __shared__ float mv[AROWS * 2];
    const int tid = threadIdx.x;
    const int r0  = blockIdx.x * AROWS;

    // stage 8 rows (coalesced float4)
    {
        const float4* src4 = (const float4*)(xin + (size_t)r0 * HDIM);
        float4* xs4 = (float4*)xs;
        for (int i = tid; i < AROWS * 256; i += 256) xs4[i] = src4[i];
    }
    __syncthreads();

    const int row = tid >> 5;   // 0..7
    const int sg  = tid & 31;

    // ---- down-proj: thread computes d[row][2 a's] over full K ----
    {
        const float4* w0 = (const float4*)Adw + (size_t)(sg * 2) * 256;
        const float4* w1 = w0 + 256;
        const float4* xr = (const float4*)xs + row * 256;
        float acc0 = 0.f, acc1 = 0.f;
#pragma unroll 4
        for (int k = 0; k < 256; ++k) {
            float4 xv = xr[k];
            float4 wa = w0[k], wb = w1[k];
            acc0 += wa.x*xv.x + wa.y*xv.y + wa.z*xv.z + wa.w*xv.w;
            acc1 += wb.x*xv.x + wb.y*xv.y + wb.z*xv.z + wb.w*xv.w;
        }
        acc0 += Adb[sg * 2];
        acc1 += Adb[sg * 2 + 1];
        dbuf[row * 64 + sg * 2]     = acc0 > 0.f ? acc0 : 0.f;
        dbuf[row * 64 + sg * 2 + 1] = acc1 > 0.f ? acc1 : 0.f;
    }
    __syncthreads();

    // ---- up-proj: thread owns 32 consecutive j for its row ----
    float4 dr[16];
    {
        const float4* dv = (const float4*)(dbuf + row * 64);
#pragma unroll
        for (int q = 0; q < 16; ++q) dr[q] = dv[q];
    }
    float y[32]; float s1 = 0.f, s2 = 0.f;
#pragma unroll 4
    for (int jj = 0; jj < 32; ++jj) {
        int jidx = sg * 32 + jj;
        const float4* urow = (const float4*)(Auw + (size_t)jidx * DA_DIM);
        float acc = xs[row * 1024 + jidx] + Aub[jidx];
#pragma unroll
        for (int q = 0; q < 16; ++q) {
            float4 uv = urow[q];
            acc += uv.x*dr[q].x + uv.y*dr[q].y + uv.z*dr[q].z + uv.w*dr[q].w;
        }
        y[jj] = acc; s1 += acc; s2 += acc * acc;
    }
    red2[(row * 32 + sg) * 2]     = s1;
    red2[(row * 32 + sg) * 2 + 1] = s2;
    __syncthreads();
    if (sg == 0) {
        float t1 = 0.f, t2 = 0.f;
        for (int q = 0; q < 32; ++q) {
            t1 += red2[(row * 32 + q) * 2];
            t2 += red2[(row * 32 + q) * 2 + 1];
        }
        float mean = t1 * (1.f / 1024.f);
        float var  = t2 * (1.f / 1024.f) - mean * mean;
        mv[row * 2]     = mean;
        mv[row * 2 + 1] = rsqrtf(var + EPS_LN);
    }
    __syncthreads();
    const float mean = mv[row * 2], rstd = mv[row * 2 + 1];
    const int rg = r0 + row;
    // normalize
#pragma unroll
    for (int jj = 0; jj < 32; ++jj) {
        int jidx = sg * 32 + jj;
        y[jj] = (y[jj] - mean) * rstd * lng[jidx] + lnb[jidx];
    }
    if (outf) {
        float4* o4 = (float4*)(outf + (size_t)rg * HDIM + sg * 32);
#pragma unroll
        for (int q = 0; q < 8; ++q) {
            float4 ov = { y[q*4], y[q*4+1], y[q*4+2], y[q*4+3] };
            o4[q] = ov;
        }
    }
    if (xfout) {
        int t = rg >> 5, b = rg & 31;
        int nb = b >> 4;
        unsigned short* base = xfout + (size_t)t * 32768;
#pragma unroll
        for (int g = 0; g < 4; ++g) {
            int lane2 = (g << 4) | (b & 15);
            unsigned short tmp[8];
#pragma unroll
            for (int e = 0; e < 8; ++e) tmp[e] = f2bf(y[g * 8 + e]);
            *(short8*)(base + (size_t)((sg * 2 + nb) * 64 + lane2) * 8) = *(short8*)tmp;
        }
    }
}

extern "C" void kernel_launch(void* const* d_in, const int* in_sizes, int n_in,
                              void* d_out, int out_size, void* d_ws, size_t ws_size,
                              hipStream_t stream)
{
    const float* x   = (const float*)d_in[0];
    const float* Wih = (const float*)d_in[1];
    const float* Whh = (const float*)d_in[2];
    const float* bih = (const float*)d_in[3];
    const float* bhh = (const float*)d_in[4];
    const float* Adw = (const float*)d_in[5];
    const float* Adb = (const float*)d_in[6];
    const float* Auw = (const float*)d_in[7];
    const float* Aub = (const float*)d_in[8];
    const float* lng = (const float*)d_in[9];
    const float* lnb = (const float*)d_in[10];
    float* out = (float*)d_out;

    // workspace carve (~84 MB)
    char* ws = (char*)d_ws;
    unsigned short* wfb  = (unsigned short*)ws; ws += (size_t)GATE4 * 2048 * 2;      // 16.78 MB
    unsigned short* xfb  = (unsigned short*)ws; ws += (size_t)T_STEPS * 32768 * 2;   // 33.55 MB
    unsigned short* ring = (unsigned short*)ws; ws += (size_t)RING * 32768 * 2;      // 33.62 MB
    float*    cbuf  = (float*)ws;    ws += (size_t)BATCH * HDIM * 4;                 // 128 KB
    unsigned* flags = (unsigned*)ws; ws += 2048;
    float* hs = out;   // alias hs onto d_out x-region (adapter is in-place safe)

    hipMemsetAsync(cbuf, 0, (size_t)BATCH * HDIM * 4, stream);
    hipMemsetAsync(ring, 0, 32768 * 2, stream);     // ring slot 0 = h0 = 0
    hipMemsetAsync(flags, 0, 2048, stream);         // flags monotonic across layers

    prep_xfrag<<<8192, 256, 0, stream>>>(x, xfb);

    for (int l = 0; l < 2; ++l) {
        prep_wfrag<<<4096, 256, 0, stream>>>(Wih + (size_t)l * GATE4 * HDIM,
                                             Whh + (size_t)l * GATE4 * HDIM, wfb);
        lstm_persistent<<<PWG, 256, 0, stream>>>(xfb, wfb, ring,
                                                 bih + (size_t)l * GATE4,
                                                 bhh + (size_t)l * GATE4,
                                                 cbuf, hs, flags,
                                                 (l * T_STEPS) % RING);

        const float* adw = Adw + (size_t)l * DA_DIM * HDIM;
        const float* adb = Adb + (size_t)l * DA_DIM;
        const float* auw = Auw + (size_t)l * HDIM * DA_DIM;
        const float* aub = Aub + (size_t)l * HDIM;
        const float* lg  = lng + (size_t)l * HDIM;
        const float* lb  = lnb + (size_t)l * HDIM;
        if (l == 0) {
            adapter_ln<<<T_STEPS * BATCH / AROWS, 256, 0, stream>>>(
                hs, adw, adb, auw, aub, lg, lb, nullptr, xfb);
        } else {
            hipMemcpyAsync(out + 16777216, hs + (size_t)511 * BATCH * HDIM,
                           (size_t)BATCH * HDIM * 4, hipMemcpyDeviceToDevice, stream);
            hipMemcpyAsync(out + 16777216 + 32768, cbuf,
                           (size_t)BATCH * HDIM * 4, hipMemcpyDeviceToDevice, stream);
            adapter_ln<<<T_STEPS * BATCH / AROWS, 256, 0, stream>>>(
                hs, adw, adb, auw, aub, lg, lb, out, nullptr);
        }
    }
}